// Round 3
// baseline (2202.570 us; speedup 1.0000x reference)
//
#include <hip/hip_runtime.h>
#include <hip/hip_bf16.h>
#include <cstdint>
#include <cstddef>

// Problem constants
#define B_     256
#define S_     196
#define DV_    2048
#define DA_    620
#define DATT_  1200
#define DATTP_ 1280   // DATT padded to 10 * BN
#define DOUT_  1024

typedef unsigned short ushort_t;
typedef __attribute__((ext_vector_type(8))) short short8;
typedef __attribute__((ext_vector_type(4))) float floatx4;

__device__ __forceinline__ float bf2f(unsigned int u) {
    union { unsigned int i; float f; } v; v.i = u << 16; return v.f;
}
__device__ __forceinline__ ushort_t f2bf(float x) {   // RNE f32->bf16
    union { float f; unsigned int u; } c; c.f = x;
    unsigned int r = (c.u + 0x7fffu + ((c.u >> 16) & 1u)) >> 16;
    return (ushort_t)r;
}

struct F4 { float v[4]; };
struct F8 { float v[8]; };

// Generic input loaders: f=1 -> fp32 buffer, f=0 -> bf16 buffer. i = element idx.
__device__ __forceinline__ F4 ld4(const void* p, size_t i, int f) {
    F4 r;
    if (f) {
        float4 u = *(const float4*)((const float*)p + i);
        r.v[0]=u.x; r.v[1]=u.y; r.v[2]=u.z; r.v[3]=u.w;
    } else {
        uint2 u = *(const uint2*)((const ushort_t*)p + i);
        r.v[0]=bf2f(u.x & 0xffffu); r.v[1]=bf2f(u.x >> 16);
        r.v[2]=bf2f(u.y & 0xffffu); r.v[3]=bf2f(u.y >> 16);
    }
    return r;
}
__device__ __forceinline__ F8 ld8(const void* p, size_t i, int f) {
    F8 r;
    if (f) {
        float4 a = *(const float4*)((const float*)p + i);
        float4 b = *(const float4*)((const float*)p + i + 4);
        r.v[0]=a.x; r.v[1]=a.y; r.v[2]=a.z; r.v[3]=a.w;
        r.v[4]=b.x; r.v[5]=b.y; r.v[6]=b.z; r.v[7]=b.w;
    } else {
        uint4 u = *(const uint4*)((const ushort_t*)p + i);
        r.v[0]=bf2f(u.x & 0xffffu); r.v[1]=bf2f(u.x >> 16);
        r.v[2]=bf2f(u.y & 0xffffu); r.v[3]=bf2f(u.y >> 16);
        r.v[4]=bf2f(u.z & 0xffffu); r.v[5]=bf2f(u.z >> 16);
        r.v[6]=bf2f(u.w & 0xffffu); r.v[7]=bf2f(u.w >> 16);
    }
    return r;
}
__device__ __forceinline__ float lds1(const void* p, size_t i, int f) {
    return f ? ((const float*)p)[i] : bf2f((unsigned int)((const ushort_t*)p)[i]);
}
__device__ __forceinline__ void stout(void* p, size_t i, float v, int f) {
    if (f) ((float*)p)[i] = v; else ((ushort_t*)p)[i] = f2bf(v);
}

// ---------------------------------------------------------------------------
// Kernel 0: dtype detector. emb ~ N(0,1). bf16 data: ~64/64 ushorts have sane
// bf16 exponents (100..140). fp32 data: only the 32 high halves do (~37/64).
// ---------------------------------------------------------------------------
__global__ __launch_bounds__(64) void k0_detect(const void* __restrict__ emb,
                                                int* __restrict__ flags)
{
    int lane = threadIdx.x;
    unsigned int u = ((const ushort_t*)emb)[lane];
    unsigned int e = (u >> 7) & 0xffu;
    bool sane = (e >= 100u && e <= 140u);
    unsigned long long m = __ballot(sane);
    if (lane == 0) flags[0] = (__popcll(m) >= 48) ? 0 : 1;   // 0=bf16, 1=fp32
}

// ---------------------------------------------------------------------------
// Kernel 1: x_a_vec gather + xa_w = relu(x_a_vec @ W_lin_a^T + b)*w_att (padded
// to 1280 with zeros) and a_feat = x_a_vec @ W_ans^T + b_ans -> out[:,1024:]
// grid 256 = bchunk(16) x rowchunk(16), block 256
// ---------------------------------------------------------------------------
__global__ __launch_bounds__(256) void k1_xa(
    const void* __restrict__ emb, const int* __restrict__ ia,
    const void* __restrict__ Wla, const void* __restrict__ bla,
    const void* __restrict__ watt,
    const void* __restrict__ Wans, const void* __restrict__ bans,
    float* __restrict__ xa_w, void* __restrict__ out,
    const int* __restrict__ flags)
{
    const int f = flags[0];
    __shared__ float xa[16][DA_];
    int t = threadIdx.x;
    int bc = blockIdx.x & 15, rc = blockIdx.x >> 4;
    int b0 = bc * 16;
    for (int idx = t; idx < 16 * 155; idx += 256) {
        int row = idx / 155, c8 = idx % 155;
        int cls = ia[b0 + row];
        cls = min(max(cls, 0), 2999);
        F4 u = ld4(emb, (size_t)cls * DA_ + c8 * 4, f);
        xa[row][c8*4+0] = u.v[0]; xa[row][c8*4+1] = u.v[1];
        xa[row][c8*4+2] = u.v[2]; xa[row][c8*4+3] = u.v[3];
    }
    __syncthreads();
    int wave = t >> 6, lane = t & 63;
    for (int j = 0; j < 36; ++j) {
        int row = rc * 144 + wave + 4 * j;   // 0..2303
        bool is_xa = row < DATTP_;
        int n = row;
        int o = row - DATTP_;
        const void* wmat = is_xa ? Wla : Wans;
        size_t wrow = is_xa ? (size_t)n * DA_ : (size_t)o * DA_;
        bool live = !(is_xa && n >= DATT_);
        float wv[12];
        if (live) {
            #pragma unroll
            for (int i = 0; i < 3; ++i) {
                int c = 4 * lane + 256 * i;
                if (c < DA_) {
                    F4 u = ld4(wmat, wrow + c, f);
                    wv[i*4+0]=u.v[0]; wv[i*4+1]=u.v[1];
                    wv[i*4+2]=u.v[2]; wv[i*4+3]=u.v[3];
                } else { wv[i*4+0]=0.f; wv[i*4+1]=0.f; wv[i*4+2]=0.f; wv[i*4+3]=0.f; }
            }
        }
        for (int bb = 0; bb < 16; ++bb) {
            float p = 0.f;
            if (live) {
                #pragma unroll
                for (int i = 0; i < 3; ++i) {
                    int c = 4 * lane + 256 * i;
                    if (c < DA_) {
                        p += wv[i*4+0]*xa[bb][c+0] + wv[i*4+1]*xa[bb][c+1]
                           + wv[i*4+2]*xa[bb][c+2] + wv[i*4+3]*xa[bb][c+3];
                    }
                }
            }
            #pragma unroll
            for (int off = 1; off < 64; off <<= 1)
                p += __shfl_xor(p, off, 64);
            if (lane == 0) {
                int b = b0 + bb;
                if (is_xa) {
                    float v = 0.f;
                    if (n < DATT_)
                        v = fmaxf(p + lds1(bla, n, f), 0.f) * lds1(watt, n, f);
                    xa_w[(size_t)b * DATTP_ + n] = v;
                } else {
                    stout(out, (size_t)b * 2048 + 1024 + o,
                          p + lds1(bans, o, f), f);
                }
            }
        }
    }
}

// ---------------------------------------------------------------------------
// Kernel 2: fused conv-GEMM + logits reduction.
// D[s, n] = relu( sum_c input_v[b,c,s] * W_conv_v[n,c] + b_conv_v[n] )
// logits[b,s] += sum_n D[s,n] * xa_w[b,n]
// BM=112 (7 m-tiles), BN=128 (8 n-tiles, 2 per wave), BK=32.
// grid = 256 b * 2 mb * 10 nb = 5120, block 256 (4 waves)
// ---------------------------------------------------------------------------
#define BM_  112
#define BN_  128
#define LDA_ 40   // 16B-aligned row stride; conflict-free b128 frag reads
#define LDB_ 40

__global__ __launch_bounds__(256) void k2_gemm(
    const void* __restrict__ iv, const void* __restrict__ Wc,
    const void* __restrict__ bcv, const float* __restrict__ xa_w,
    float* __restrict__ logits, const int* __restrict__ flags)
{
    const int f = flags[0];
    __shared__ ushort_t Al[BM_ * LDA_];
    __shared__ ushort_t Bl[BN_ * LDB_];
    __shared__ float llog[BM_];

    int t = threadIdx.x;
    int bid = blockIdx.x;
    int b   = bid / 20;
    int rem = bid % 20;
    int mb = rem / 10, nb = rem % 10;
    int s0 = mb * BM_, n0 = nb * BN_;
    int rows_valid = min(BM_, S_ - s0);        // 112 or 84
    int cpc = (rows_valid + 7) >> 3;           // s-chunks per channel: 14 or 11
    int totA = 32 * cpc;

    if (t < BM_) llog[t] = 0.f;
    // Zero-fill A-tile tail rows once (never written in the K-loop).
    for (int idx = t; idx < (BM_ - rows_valid) * LDA_; idx += 256)
        Al[rows_valid * LDA_ + idx] = 0;

    size_t ivbase = (size_t)b * DV_ * S_;

    int wave = t >> 6, lane = t & 63;
    int lquad = lane >> 4, l15 = lane & 15;
    int nbase = wave * 32;                     // 2 n-tiles per wave

    floatx4 acc[7][2];
    #pragma unroll
    for (int mt = 0; mt < 7; ++mt) {
        acc[mt][0] = floatx4{0.f, 0.f, 0.f, 0.f};
        acc[mt][1] = floatx4{0.f, 0.f, 0.f, 0.f};
    }

    for (int kt = 0; kt < DV_ / 32; ++kt) {
        int k0 = kt * 32;
        __syncthreads();
        // A staging: transpose [c][s] -> Al[s][c] (bf16), 8-row chunks.
        for (int idx = t; idx < totA; idx += 256) {
            int c = idx & 31, j = idx >> 5;
            int sr = min(8 * j, rows_valid - 8);
            F8 u = ld8(iv, ivbase + (size_t)(k0 + c) * S_ + s0 + sr, f);
            #pragma unroll
            for (int i = 0; i < 8; ++i)
                Al[(sr + i) * LDA_ + c] = f2bf(u.v[i]);
        }
        // B staging: Bl[n][k] = Wc[n0+n][k0+k] (bf16); pad rows zeroed.
        for (int idx = t; idx < 512; idx += 256) {
            int nl = idx >> 2, kc = idx & 3;
            int ng = n0 + nl;
            if (ng < DATT_) {
                F8 u = ld8(Wc, (size_t)ng * DV_ + k0 + kc * 8, f);
                #pragma unroll
                for (int i = 0; i < 8; ++i)
                    Bl[nl * LDB_ + kc * 8 + i] = f2bf(u.v[i]);
            } else {
                #pragma unroll
                for (int i = 0; i < 8; ++i)
                    Bl[nl * LDB_ + kc * 8 + i] = 0;
            }
        }
        __syncthreads();
        // compute: 7 m-tiles x 2 n-tiles per wave
        short8 bf0 = *(const short8*)&Bl[(nbase + l15) * LDB_ + lquad * 8];
        short8 bf1 = *(const short8*)&Bl[(nbase + 16 + l15) * LDB_ + lquad * 8];
        #pragma unroll
        for (int mt = 0; mt < 7; ++mt) {
            short8 af = *(const short8*)&Al[(mt * 16 + l15) * LDA_ + lquad * 8];
            acc[mt][0] = __builtin_amdgcn_mfma_f32_16x16x32_bf16(af, bf0, acc[mt][0], 0, 0, 0);
            acc[mt][1] = __builtin_amdgcn_mfma_f32_16x16x32_bf16(af, bf1, acc[mt][1], 0, 0, 0);
        }
    }

    // Epilogue: relu(acc + bias) * xa_w, reduce over n.
    // C/D layout (16x16x32): col(n) = lane&15, row(s) = (lane>>4)*4 + reg.
    float bias[2], xw[2];
    #pragma unroll
    for (int bt = 0; bt < 2; ++bt) {
        int ng = n0 + nbase + bt * 16 + l15;
        bias[bt] = (ng < DATT_) ? lds1(bcv, ng, f) : 0.f;
        xw[bt]   = (ng < DATT_) ? xa_w[(size_t)b * DATTP_ + ng] : 0.f;
    }
    float plog[7][4];
    #pragma unroll
    for (int mt = 0; mt < 7; ++mt)
        #pragma unroll
        for (int r = 0; r < 4; ++r) {
            float v0 = fmaxf(acc[mt][0][r] + bias[0], 0.f) * xw[0];
            float v1 = fmaxf(acc[mt][1][r] + bias[1], 0.f) * xw[1];
            plog[mt][r] = v0 + v1;
        }
    #pragma unroll
    for (int off = 1; off <= 8; off <<= 1)
        #pragma unroll
        for (int mt = 0; mt < 7; ++mt)
            #pragma unroll
            for (int r = 0; r < 4; ++r)
                plog[mt][r] += __shfl_xor(plog[mt][r], off, 64);
    if (l15 == 0) {
        #pragma unroll
        for (int mt = 0; mt < 7; ++mt)
            #pragma unroll
            for (int r = 0; r < 4; ++r)
                atomicAdd(&llog[mt * 16 + lquad * 4 + r], plog[mt][r]);
    }
    __syncthreads();
    if (t < rows_valid)
        atomicAdd(&logits[(size_t)b * 256 + s0 + t], llog[t]);
}

// ---------------------------------------------------------------------------
// Kernel 3a: softmax over s (196) per b, IN PLACE. b_att omitted (shift-inv).
// Bit-pattern non-finite canary (fast-math-proof).
// ---------------------------------------------------------------------------
__global__ __launch_bounds__(64) void k3a_softmax(float* __restrict__ logits)
{
    int b = blockIdx.x, lane = threadIdx.x;
    float v[4]; float mx = -1e30f;
    #pragma unroll
    for (int i = 0; i < 4; ++i) {
        int s = lane + 64 * i;
        v[i] = (s < S_) ? logits[(size_t)b * 256 + s] : -1e30f;
        union { float f; unsigned u; } cv; cv.f = v[i];
        if ((cv.u & 0x7f800000u) == 0x7f800000u) v[i] = -1e30f;
        mx = fmaxf(mx, v[i]);
    }
    #pragma unroll
    for (int off = 1; off < 64; off <<= 1)
        mx = fmaxf(mx, __shfl_xor(mx, off, 64));
    float e[4]; float sum = 0.f;
    #pragma unroll
    for (int i = 0; i < 4; ++i) {
        int s = lane + 64 * i;
        e[i] = (s < S_) ? __expf(v[i] - mx) : 0.f;
        sum += e[i];
    }
    #pragma unroll
    for (int off = 1; off < 64; off <<= 1)
        sum += __shfl_xor(sum, off, 64);
    float inv = 1.f / sum;
    #pragma unroll
    for (int i = 0; i < 4; ++i) {
        int s = lane + 64 * i;
        if (s < S_) logits[(size_t)b * 256 + s] = e[i] * inv;
    }
}

// ---------------------------------------------------------------------------
// Kernel 3b: x_v_att[b,d] = sum_s attn[b,s] * input_v[b,d,s]
// grid 2048 = b(256) x dchunk(8), block 256
// ---------------------------------------------------------------------------
__global__ __launch_bounds__(256) void k3b_wsum(
    const void* __restrict__ iv, const float* __restrict__ attn,
    float* __restrict__ xvatt, const int* __restrict__ flags)
{
    const int f = flags[0];
    __shared__ float at[200];
    int t = threadIdx.x;
    int b = blockIdx.x >> 3, dc = blockIdx.x & 7;
    if (t < S_) at[t] = attn[(size_t)b * 256 + t];
    __syncthreads();
    int d = dc * 256 + t;
    size_t rowb = ((size_t)b * DV_ + d) * S_;
    float acc = 0.f;
    #pragma unroll 7
    for (int i = 0; i < 49; ++i) {
        F4 u = ld4(iv, rowb + 4 * i, f);
        acc += u.v[0] * at[4*i+0];
        acc += u.v[1] * at[4*i+1];
        acc += u.v[2] * at[4*i+2];
        acc += u.v[3] * at[4*i+3];
    }
    xvatt[(size_t)b * DV_ + d] = acc;
}

// ---------------------------------------------------------------------------
// Kernel 3c: v_feat = x_v_att @ W_img^T + b_img -> out[:, :1024]
// grid 256 = ochunk(16, 64 rows) x bchunk(16)
// ---------------------------------------------------------------------------
__global__ __launch_bounds__(256) void k3c_vfeat(
    const float* __restrict__ xvatt, const void* __restrict__ Wimg,
    const void* __restrict__ bimg, void* __restrict__ out,
    const int* __restrict__ flags)
{
    const int f = flags[0];
    __shared__ float xv[DV_];
    int t = threadIdx.x;
    int oc = blockIdx.x >> 4, bc2 = blockIdx.x & 15;
    int o0 = oc * 64, b0 = bc2 * 16;
    int wave = t >> 6, lane = t & 63;
    for (int bb = 0; bb < 16; ++bb) {
        int b = b0 + bb;
        __syncthreads();
        {
            const float4* src = (const float4*)(xvatt + (size_t)b * DV_);
            float4* dst = (float4*)xv;
            dst[t] = src[t];
            dst[t + 256] = src[t + 256];
        }
        __syncthreads();
        for (int j = 0; j < 16; ++j) {
            int o = o0 + wave * 16 + j;
            size_t wrow = (size_t)o * DV_;
            float p = 0.f;
            #pragma unroll
            for (int i = 0; i < 4; ++i) {
                int c = 8 * lane + 512 * i;
                F8 u = ld8(Wimg, wrow + c, f);
                p += u.v[0]*xv[c+0] + u.v[1]*xv[c+1] + u.v[2]*xv[c+2] + u.v[3]*xv[c+3];
                p += u.v[4]*xv[c+4] + u.v[5]*xv[c+5] + u.v[6]*xv[c+6] + u.v[7]*xv[c+7];
            }
            #pragma unroll
            for (int off = 1; off < 64; off <<= 1)
                p += __shfl_xor(p, off, 64);
            if (lane == 0)
                stout(out, (size_t)b * 2048 + o, p + lds1(bimg, o, f), f);
        }
    }
}

// ---------------------------------------------------------------------------
extern "C" void kernel_launch(void* const* d_in, const int* in_sizes, int n_in,
                              void* d_out, int out_size, void* d_ws, size_t ws_size,
                              hipStream_t stream)
{
    const void* iv   = d_in[0];   // input_v  [256,2048,196]
    const void* emb  = d_in[1];   // emb      [3000,620]
    const void* Wc   = d_in[2];   // W_conv_v [1200,2048]
    const void* bcv  = d_in[3];   // b_conv_v [1200]
    const void* Wla  = d_in[4];   // W_lin_a  [1200,620]
    const void* bla  = d_in[5];   // b_lin_a  [1200]
    const void* watt = d_in[6];   // w_att    [1200]
    // d_in[7] = b_att: softmax shift-invariant, unused
    const void* Wimg = d_in[8];   // W_img    [1024,2048]
    const void* bimg = d_in[9];   // b_img    [1024]
    const void* Wans = d_in[10];  // W_ans    [1024,620]
    const void* bans = d_in[11];  // b_ans    [1024]
    const int*  ia   = (const int*)d_in[12];  // input_a [256] int32

    char* ws = (char*)d_ws;
    float* xa_w   = (float*)(ws);                      // 1,310,720 B
    float* logits = (float*)(ws + 1310720);            //   262,144 B (attn in-place)
    float* xvatt  = (float*)(ws + 1310720 + 262144);   // 2,097,152 B
    int*   flags  = (int*)(ws + 1310720 + 262144 + 2097152);

    hipMemsetAsync(logits, 0, 256 * 256 * 4, stream);
    k0_detect<<<1, 64, 0, stream>>>(emb, flags);
    k1_xa<<<256, 256, 0, stream>>>(emb, ia, Wla, bla, watt, Wans, bans, xa_w, d_out, flags);
    k2_gemm<<<5120, 256, 0, stream>>>(iv, Wc, bcv, xa_w, logits, flags);
    k3a_softmax<<<256, 64, 0, stream>>>(logits);
    k3b_wsum<<<2048, 256, 0, stream>>>(iv, logits, xvatt, flags);
    k3c_vfeat<<<256, 256, 0, stream>>>(xvatt, Wimg, bimg, d_out, flags);
}